// Round 8
// baseline (509.044 us; speedup 1.0000x reference)
//
#include <hip/hip_runtime.h>

#define Bc 1024
#define Tc 512
#define Ic 64
#define Hc 32
#define NB 16            // batches per block
#define TT 8             // timesteps per tile
#define NT (Tc / TT)     // 64 tiles
#define XP2 36           // xqlds h-pitch (f32)
#define L2E2 2.8853900817779268f  // 2*log2(e)

typedef __bf16   bf16x8 __attribute__((ext_vector_type(8)));
typedef _Float16 half8  __attribute__((ext_vector_type(8)));
typedef float    f32x4  __attribute__((ext_vector_type(4)));
typedef unsigned u32x4  __attribute__((ext_vector_type(4)));
typedef unsigned uint2v __attribute__((ext_vector_type(2)));

__device__ inline bf16x8 to_bf16x8(float4 u0, float4 u1) {
    bf16x8 t;
    t[0] = (__bf16)u0.x; t[1] = (__bf16)u0.y; t[2] = (__bf16)u0.z; t[3] = (__bf16)u0.w;
    t[4] = (__bf16)u1.x; t[5] = (__bf16)u1.y; t[6] = (__bf16)u1.z; t[7] = (__bf16)u1.w;
    return t;
}
__device__ inline bf16x8 to_bf16x8s(float4 u0, float4 u1, float s) {
    bf16x8 t;
    t[0] = (__bf16)(u0.x*s); t[1] = (__bf16)(u0.y*s); t[2] = (__bf16)(u0.z*s); t[3] = (__bf16)(u0.w*s);
    t[4] = (__bf16)(u1.x*s); t[5] = (__bf16)(u1.y*s); t[6] = (__bf16)(u1.z*s); t[7] = (__bf16)(u1.w*s);
    return t;
}

// ---------------------------------------------------------------------------
// R13: MFMA recurrence. Scan wave: per step 2x mfma_f32_16x16x32_f16
// (D[h 0..15|16..31][batch16] = W'(f16) x state + xq-C(f32)), tanh via
// exp2+rcp, state repack D->B = 4 pkrtz + {id, rsw16, rsw32, rsw16}
// (bijective for ANY swap semantics; sigma discovered by integer simulation
// at init, A-weights loaded pre-permuted by sigma). 16 batches/wave,
// 64 blocks x 2 waves. Helper wave: phase-1 x-projection (batch-rows MFMA,
// verified layout) into triple-buffered f32 xq tiles + out-reduction;
// 8-slot rolling x prefetch covers HBM latency. Barrier per 8 steps.
// Folded into C: L2E2*(x.Wih + bih + bhh + rowsum(Whh)); A = -2*L2E2*Whh.
// r = 1/(1+2^D); h = 1-2r; out = (sum(Wout)+bo) + sum(-2Wout.r).
// ---------------------------------------------------------------------------

#if __has_builtin(__builtin_amdgcn_permlane16_swap)
#define PLSWAP(A, B)                                                          \
    { uint2v _t = __builtin_amdgcn_permlane16_swap((A), (B), false, false);   \
      (A) = _t[0]; (B) = _t[1]; }
#else
#define PLSWAP(A, B)                                                          \
    asm("s_nop 1\n\tv_permlane16_swap_b32 %0, %1" : "+v"(A), "+v"(B));
#endif
#if __has_builtin(__builtin_amdgcn_permlane32_swap)
#define P32SWAP(A, B)                                                         \
    { uint2v _t = __builtin_amdgcn_permlane32_swap((A), (B), false, false);   \
      (A) = _t[0]; (B) = _t[1]; }
#else
#define P32SWAP(A, B)                                                         \
    asm("s_nop 1\n\tv_permlane32_swap_b32 %0, %1" : "+v"(A), "+v"(B));
#endif

// per-lane-psel row swaps (psel discovered at init; assembles the true
// involution from the two outputs under any HW output convention)
#define RSW16(X, OUT) { unsigned a__=(X), b__=(X); PLSWAP(a__,b__); OUT = ps16 ? a__ : b__; }
#define RSW32(X, OUT) { unsigned a__=(X), b__=(X); P32SWAP(a__,b__); OUT = ps32 ? a__ : b__; }

#define PK(a, b) __builtin_bit_cast(unsigned, __builtin_amdgcn_cvt_pkrtz((a), (b)))

// ---------------- scan step ------------------------------------------------
#define SSTEP(CC1, CC2, CN1, CN2, uu, tpf, upf)                               \
    {                                                                         \
        const float* pf_ = xqlds + (((tpf) % 3) * TT + (upf)) * (NB * XP2)    \
                           + n * XP2 + 4 * q;                                 \
        CN1 = *(const f32x4*)pf_;                                             \
        CN2 = *(const f32x4*)(pf_ + 16);                                      \
        const f32x4 D1_ = __builtin_amdgcn_mfma_f32_16x16x32_f16(A1f, Bst, CC1, 0, 0, 0); \
        const f32x4 D2_ = __builtin_amdgcn_mfma_f32_16x16x32_f16(A2f, Bst, CC2, 0, 0, 0); \
        r10 = __builtin_amdgcn_rcpf(__builtin_amdgcn_exp2f(D1_[0]) + 1.0f);   \
        r11 = __builtin_amdgcn_rcpf(__builtin_amdgcn_exp2f(D1_[1]) + 1.0f);   \
        r12 = __builtin_amdgcn_rcpf(__builtin_amdgcn_exp2f(D1_[2]) + 1.0f);   \
        r13 = __builtin_amdgcn_rcpf(__builtin_amdgcn_exp2f(D1_[3]) + 1.0f);   \
        r20 = __builtin_amdgcn_rcpf(__builtin_amdgcn_exp2f(D2_[0]) + 1.0f);   \
        r21 = __builtin_amdgcn_rcpf(__builtin_amdgcn_exp2f(D2_[1]) + 1.0f);   \
        r22 = __builtin_amdgcn_rcpf(__builtin_amdgcn_exp2f(D2_[2]) + 1.0f);   \
        r23 = __builtin_amdgcn_rcpf(__builtin_amdgcn_exp2f(D2_[3]) + 1.0f);   \
        const unsigned G0_ = PK(r10, r20), G1_ = PK(r11, r21);                \
        const unsigned G2_ = PK(r12, r22), G3_ = PK(r13, r23);                \
        unsigned B1_, B2_, B3_;                                               \
        RSW16(G1_, B1_) RSW32(G2_, B2_) RSW16(G3_, B3_)                       \
        u32x4 bu_; bu_[0] = G0_; bu_[1] = B1_; bu_[2] = B2_; bu_[3] = B3_;    \
        Bst = __builtin_bit_cast(half8, bu_);                                 \
        pbuf[(((tb & 1) * TT + (uu)) * NB + n) * 4 + q] =                     \
            fmaf(r10, w2a0, fmaf(r11, w2a1, fmaf(r12, w2a2, fmaf(r13, w2a3,  \
            fmaf(r20, w2b0, fmaf(r21, w2b1, fmaf(r22, w2b2, r23 * w2b3)))))));\
    }

// ---------------- helper: phase-1 slot macros ------------------------------
#define XDECL(S) float4 X##S##0, X##S##1, X##S##2, X##S##3;

#define HLOAD(S, wt)                                                          \
    if ((wt) < Tc) {                                                          \
        const float* xp_ = x + ((size_t)(b0 + n) * Tc + (wt)) * Ic + q * 8;   \
        X##S##0 = ((const float4*)xp_)[0];                                    \
        X##S##1 = ((const float4*)xp_)[1];                                    \
        X##S##2 = ((const float4*)(xp_ + 32))[0];                             \
        X##S##3 = ((const float4*)(xp_ + 32))[1];                             \
    }

#define HMFMA(S, wt)                                                          \
    if ((wt) < Tc) {                                                          \
        const bf16x8 A0_ = to_bf16x8(X##S##0, X##S##1);                       \
        const bf16x8 A1_ = to_bf16x8(X##S##2, X##S##3);                       \
        f32x4 d1_ = CbH1, d2_ = CbH2;                                         \
        d1_ = __builtin_amdgcn_mfma_f32_16x16x32_bf16(A0_, Pw00, d1_, 0,0,0); \
        d1_ = __builtin_amdgcn_mfma_f32_16x16x32_bf16(A1_, Pw01, d1_, 0,0,0); \
        d2_ = __builtin_amdgcn_mfma_f32_16x16x32_bf16(A0_, Pw10, d2_, 0,0,0); \
        d2_ = __builtin_amdgcn_mfma_f32_16x16x32_bf16(A1_, Pw11, d2_, 0,0,0); \
        float* wb_ = xqlds + ((((wt) >> 3) % 3) * TT + ((wt) & 7)) * (NB * XP2); \
        wb_[(4*q + 0) * XP2 + n]      = d1_[0];                               \
        wb_[(4*q + 1) * XP2 + n]      = d1_[1];                               \
        wb_[(4*q + 2) * XP2 + n]      = d1_[2];                               \
        wb_[(4*q + 3) * XP2 + n]      = d1_[3];                               \
        wb_[(4*q + 0) * XP2 + n + 16] = d2_[0];                               \
        wb_[(4*q + 1) * XP2 + n + 16] = d2_[1];                               \
        wb_[(4*q + 2) * XP2 + n + 16] = d2_[2];                               \
        wb_[(4*q + 3) * XP2 + n + 16] = d2_[3];                               \
    }

#define HSTEP(S, wt, wtn) HMFMA(S, wt) HLOAD(S, wtn)

#define HRED(tbr)                                                             \
    {                                                                         \
        const int n2_ = lane >> 2, ug_ = (lane & 3) * 2;                      \
        const float* pr_ = pbuf + ((((tbr) & 1) * TT + ug_) * NB + n2_) * 4;  \
        const f32x4 pa_ = *(const f32x4*)pr_;                                 \
        const f32x4 pb_ = *(const f32x4*)(pr_ + NB * 4);                      \
        float2 sv_;                                                           \
        sv_.x = ((pa_[0] + pa_[1]) + (pa_[2] + pa_[3])) + cst;                \
        sv_.y = ((pb_[0] + pb_[1]) + (pb_[2] + pb_[3])) + cst;                \
        *(float2*)(out + (size_t)(b0 + n2_) * Tc + (tbr) * TT + ug_) = sv_;   \
    }

__global__ __launch_bounds__(128, 1) void fused_rnn_kernel(
    const float* __restrict__ x, const float* __restrict__ Wih,
    const float* __restrict__ bih, const float* __restrict__ h0,
    const float* __restrict__ Whh, const float* __restrict__ bhh,
    const float* __restrict__ Wout, const float* __restrict__ bout,
    float* __restrict__ out)
{
    __shared__ float xqlds[3 * TT * NB * XP2];  // 55296 B (f32 xq tiles)
    __shared__ float pbuf[2 * TT * NB * 4];     // 4096 B

    const int tid  = threadIdx.x;
    const int wid  = tid >> 6;       // 0 = scan, 1 = helper
    const int lane = tid & 63;
    const int n    = lane & 15;      // batch-col / h-col / A-row
    const int q    = lane >> 4;      // k-quad / D-row-quad
    const int b0   = blockIdx.x * NB;

    // ---------------- shared declarations (per-wave usage) -----------------
    // scan state
    bool ps16 = false, ps32 = false;
    half8 A1f = {}, A2f = {}, Bst = {};
    f32x4 Ca1 = {}, Ca2 = {}, Cb1 = {}, Cb2 = {};
    float w2a0=0,w2a1=0,w2a2=0,w2a3=0,w2b0=0,w2b1=0,w2b2=0,w2b3=0;
    float r10=0,r11=0,r12=0,r13=0,r20=0,r21=0,r22=0,r23=0;
    // helper state
    bf16x8 Pw00, Pw01, Pw10, Pw11;
    f32x4 CbH1 = {}, CbH2 = {};
    float cst = 0.f;
    XDECL(0) XDECL(1) XDECL(2) XDECL(3) XDECL(4) XDECL(5) XDECL(6) XDECL(7)

    if (wid == 1) {
        // ---------------- helper init --------------------------------------
#pragma unroll
        for (int hh = 0; hh < 2; ++hh)
#pragma unroll
            for (int kh = 0; kh < 2; ++kh) {
                const float* wp = Wih + (n + 16 * hh) * Ic + q * 8 + kh * 32;
                const bf16x8 f = to_bf16x8s(((const float4*)wp)[0],
                                            ((const float4*)wp)[1], L2E2);
                if (hh == 0 && kh == 0) Pw00 = f;
                else if (hh == 0)       Pw01 = f;
                else if (kh == 0)       Pw10 = f;
                else                    Pw11 = f;
            }
        // C-bias: L2E2*(bih + bhh + rowsum(Whh)) per h
        float rs1 = 0.f, rs2 = 0.f;
        {
            const float4* wr1 = (const float4*)(Whh + n * Hc);
            const float4* wr2 = (const float4*)(Whh + (n + 16) * Hc);
#pragma unroll
            for (int j = 0; j < 8; ++j) {
                const float4 a = wr1[j], b = wr2[j];
                rs1 += (a.x + a.y) + (a.z + a.w);
                rs2 += (b.x + b.y) + (b.z + b.w);
            }
        }
        const float cb1 = (bih[n] + bhh[n] + rs1) * L2E2;
        const float cb2 = (bih[n + 16] + bhh[n + 16] + rs2) * L2E2;
        CbH1[0] = cb1; CbH1[1] = cb1; CbH1[2] = cb1; CbH1[3] = cb1;
        CbH2[0] = cb2; CbH2[1] = cb2; CbH2[2] = cb2; CbH2[3] = cb2;
        // out constant: sum(Wout) + bo
        {
            const float4* wo4 = (const float4*)Wout;
            float s = 0.f;
#pragma unroll
            for (int j = 0; j < 8; ++j) {
                const float4 a = wo4[j];
                s += (a.x + a.y) + (a.z + a.w);
            }
            cst = s + bout[0];
        }
        // prologue: fill tiles 0,1 into buf0,buf1; leave tile2 in regs
        HLOAD(0, 0) HLOAD(1, 1) HLOAD(2, 2) HLOAD(3, 3)
        HLOAD(4, 4) HLOAD(5, 5) HLOAD(6, 6) HLOAD(7, 7)
        HSTEP(0, 0, 8)  HSTEP(1, 1, 9)  HSTEP(2, 2, 10) HSTEP(3, 3, 11)
        HSTEP(4, 4, 12) HSTEP(5, 5, 13) HSTEP(6, 6, 14) HSTEP(7, 7, 15)
        HSTEP(0, 8, 16)  HSTEP(1, 9, 17)  HSTEP(2, 10, 18) HSTEP(3, 11, 19)
        HSTEP(4, 12, 20) HSTEP(5, 13, 21) HSTEP(6, 14, 22) HSTEP(7, 15, 23)
    } else {
        // ---------------- scan init ----------------------------------------
        // psel discovery (per-lane; robust to swap-output convention)
        {
            unsigned d0 = (unsigned)lane, d1 = (unsigned)lane;
            PLSWAP(d0, d1)
            ps16 = (d0 == (unsigned)(lane ^ 16));
            unsigned e0 = (unsigned)lane, e1 = (unsigned)lane;
            P32SWAP(e0, e1)
            ps32 = (e0 == (unsigned)(lane ^ 32));
        }
        // sigma discovery: run the repack network on packed h-indices
        u32x4 Bsv;
        {
            const unsigned g0 = (unsigned)(4*q + 0) | ((unsigned)(16 + 4*q + 0) << 16);
            const unsigned g1 = (unsigned)(4*q + 1) | ((unsigned)(16 + 4*q + 1) << 16);
            const unsigned g2 = (unsigned)(4*q + 2) | ((unsigned)(16 + 4*q + 2) << 16);
            const unsigned g3 = (unsigned)(4*q + 3) | ((unsigned)(16 + 4*q + 3) << 16);
            unsigned s1, s2, s3;
            RSW16(g1, s1) RSW32(g2, s2) RSW16(g3, s3)
            Bsv[0] = g0; Bsv[1] = s1; Bsv[2] = s2; Bsv[3] = s3;
        }
        // A-weights pre-permuted by sigma: A1 row = n (h_out), A2 row = n+16
        {
            const float cw = -2.0f * L2E2;
            const float* w0r = Whh + n * Hc;
            const float* w1r = Whh + (n + 16) * Hc;
            u32x4 aw1, aw2;
#pragma unroll
            for (int jp = 0; jp < 4; ++jp) {
                const unsigned lo = Bsv[jp] & 0xFFFFu, hi = Bsv[jp] >> 16;
                aw1[jp] = PK(w0r[lo] * cw, w0r[hi] * cw);
                aw2[jp] = PK(w1r[lo] * cw, w1r[hi] * cw);
            }
            A1f = __builtin_bit_cast(half8, aw1);
            A2f = __builtin_bit_cast(half8, aw2);
        }
        // output-dot slot constants
        w2a0 = -2.0f * Wout[4*q + 0]; w2a1 = -2.0f * Wout[4*q + 1];
        w2a2 = -2.0f * Wout[4*q + 2]; w2a3 = -2.0f * Wout[4*q + 3];
        w2b0 = -2.0f * Wout[16 + 4*q + 0]; w2b1 = -2.0f * Wout[16 + 4*q + 1];
        w2b2 = -2.0f * Wout[16 + 4*q + 2]; w2b3 = -2.0f * Wout[16 + 4*q + 3];
        // initial state r = (1-h)/2: B in sigma order, r-regs in own order
        {
            const float* h0p = h0 + (size_t)(b0 + n) * Hc;
            u32x4 bi;
#pragma unroll
            for (int jp = 0; jp < 4; ++jp) {
                const unsigned lo = Bsv[jp] & 0xFFFFu, hi = Bsv[jp] >> 16;
                bi[jp] = PK(fmaf(-0.5f, h0p[lo], 0.5f),
                            fmaf(-0.5f, h0p[hi], 0.5f));
            }
            Bst = __builtin_bit_cast(half8, bi);
            r10 = fmaf(-0.5f, h0p[4*q + 0], 0.5f);
            r11 = fmaf(-0.5f, h0p[4*q + 1], 0.5f);
            r12 = fmaf(-0.5f, h0p[4*q + 2], 0.5f);
            r13 = fmaf(-0.5f, h0p[4*q + 3], 0.5f);
            r20 = fmaf(-0.5f, h0p[16 + 4*q + 0], 0.5f);
            r21 = fmaf(-0.5f, h0p[16 + 4*q + 1], 0.5f);
            r22 = fmaf(-0.5f, h0p[16 + 4*q + 2], 0.5f);
            r23 = fmaf(-0.5f, h0p[16 + 4*q + 3], 0.5f);
        }
    }
    __syncthreads();   // tiles 0,1 visible

    if (wid == 0) {
        // first C (tile 0, u=0; buf0)
        const float* pf = xqlds + n * XP2 + 4 * q;
        Ca1 = *(const f32x4*)pf;
        Ca2 = *(const f32x4*)(pf + 16);
    }

#pragma unroll 1
    for (int tb = 0; tb < NT; ++tb) {
        if (wid == 0) {
            const int tn = (tb + 1 < NT) ? tb + 1 : tb;
            SSTEP(Ca1, Ca2, Cb1, Cb2, 0, tb, 1)
            SSTEP(Cb1, Cb2, Ca1, Ca2, 1, tb, 2)
            SSTEP(Ca1, Ca2, Cb1, Cb2, 2, tb, 3)
            SSTEP(Cb1, Cb2, Ca1, Ca2, 3, tb, 4)
            SSTEP(Ca1, Ca2, Cb1, Cb2, 4, tb, 5)
            SSTEP(Cb1, Cb2, Ca1, Ca2, 5, tb, 6)
            SSTEP(Ca1, Ca2, Cb1, Cb2, 6, tb, 7)
            SSTEP(Cb1, Cb2, Ca1, Ca2, 7, tn, 0)
        } else {
            // write tile tb+2 (consume slot bank), refill with tile tb+3
            const int wb = (tb + 2) * TT, wl = (tb + 3) * TT;
            HSTEP(0, wb + 0, wl + 0) HSTEP(1, wb + 1, wl + 1)
            HSTEP(2, wb + 2, wl + 2) HSTEP(3, wb + 3, wl + 3)
            HSTEP(4, wb + 4, wl + 4) HSTEP(5, wb + 5, wl + 5)
            HSTEP(6, wb + 6, wl + 6) HSTEP(7, wb + 7, wl + 7)
            if (tb >= 1) HRED(tb - 1)
        }
        __syncthreads();
    }

    if (wid == 1) {
        HRED(NT - 1)
    } else {
        // h_last: [1, B, H] appended after outs [B, T, 1]; h = 1 - 2r
        float* hl = out + (size_t)Bc * Tc + (size_t)(b0 + n) * Hc;
        float4 v1, v2;
        v1.x = fmaf(-2.0f, r10, 1.0f); v1.y = fmaf(-2.0f, r11, 1.0f);
        v1.z = fmaf(-2.0f, r12, 1.0f); v1.w = fmaf(-2.0f, r13, 1.0f);
        v2.x = fmaf(-2.0f, r20, 1.0f); v2.y = fmaf(-2.0f, r21, 1.0f);
        v2.z = fmaf(-2.0f, r22, 1.0f); v2.w = fmaf(-2.0f, r23, 1.0f);
        *(float4*)(hl + 4 * q)      = v1;
        *(float4*)(hl + 16 + 4 * q) = v2;
    }
}

extern "C" void kernel_launch(void* const* d_in, const int* in_sizes, int n_in,
                              void* d_out, int out_size, void* d_ws, size_t ws_size,
                              hipStream_t stream) {
    const float* x    = (const float*)d_in[0];
    const float* h0   = (const float*)d_in[1];
    const float* Wih  = (const float*)d_in[2];
    const float* bih  = (const float*)d_in[3];
    const float* Whh  = (const float*)d_in[4];
    const float* bhh  = (const float*)d_in[5];
    const float* Wout = (const float*)d_in[6];
    const float* bout = (const float*)d_in[7];
    float* out = (float*)d_out;

    fused_rnn_kernel<<<Bc / NB, 128, 0, stream>>>(x, Wih, bih, h0, Whh, bhh,
                                                  Wout, bout, out);
}

// Round 9
// 229.355 us; speedup vs baseline: 2.2195x; 2.2195x over previous
//
#include <hip/hip_runtime.h>

#define Bc 1024
#define Tc 512
#define Ic 64
#define Hc 32
#define L2E2 2.8853900817779268f   // 2*log2(e): tanh(a) = 1 - 2/(2^(a*L2E2)+1)

// xt transpose tile: [2 buf][32 h][24 t-pitch] bf16 (16 used; 48B rows)
#define XT_ROW 24
#define XT_BUF (Hc * XT_ROW)       // 768 elems per buffer

typedef __bf16 bf16x8 __attribute__((ext_vector_type(8)));
typedef __bf16 bf16x4 __attribute__((ext_vector_type(4)));
typedef float  f32x4  __attribute__((ext_vector_type(4)));
typedef _Float16 half2v __attribute__((ext_vector_type(2)));
typedef unsigned uint2v __attribute__((ext_vector_type(2)));

__device__ inline bf16x8 to_bf16x8(float4 u0, float4 u1) {
    bf16x8 t;
    t[0] = (__bf16)u0.x; t[1] = (__bf16)u0.y; t[2] = (__bf16)u0.z; t[3] = (__bf16)u0.w;
    t[4] = (__bf16)u1.x; t[5] = (__bf16)u1.y; t[6] = (__bf16)u1.z; t[7] = (__bf16)u1.w;
    return t;
}
__device__ inline bf16x8 to_bf16x8s(float4 u0, float4 u1, float s) {
    bf16x8 t;
    t[0] = (__bf16)(u0.x*s); t[1] = (__bf16)(u0.y*s); t[2] = (__bf16)(u0.z*s); t[3] = (__bf16)(u0.w*s);
    t[4] = (__bf16)(u1.x*s); t[5] = (__bf16)(u1.y*s); t[6] = (__bf16)(u1.z*s); t[7] = (__bf16)(u1.w*s);
    return t;
}

// ---------------------------------------------------------------------------
// R14: R11 skeleton (best measured: 365 cyc/step), full-dot chain cut.
// Model from R8-R13: wall = chain-links x ~22cy; per-step issue (~2cy/inst)
// hides under the chain. R13 (MFMA recurrence) refuted: 1722 cyc/step.
// Changes vs R11 (ONLY the gather+dot; tail/tiles/reduce identical):
//  - gather: 15x depth-1 row_ror from c (was ror8 -> cndmask -> ror: 2 extra
//    links). Rotations 0..15 are bijections covering all 16 packed pairs.
//  - dot: FULL 32-MAC dot per lane, 16 fdot2 in 4 chains + 2-level tree
//    (was half-dot + P32SWAP + combine-add: 2 extra links). Rows r, r+2
//    duplicate the same h -- harmless (identical values, same pbuf addr).
//  - weights: 16 per-lane f16 pairs via the SAME index-simulation trick.
//  - xq scale 0.5*L2E2 -> L2E2, bch now full (single chain adds each once).
// Chain: RORD -> fdot x4 -> tree x2 -> exp2 -> +1 -> rcp -> PLSWAP -> cnd
// -> cnd -> pkrtz = 14 links (R11: 16-17). 1 batch/block, 1024 blocks.
// ---------------------------------------------------------------------------

// DPP row-rotate-right by N within 16-lane rows (all lanes valid)
#define RORD(dst, src, N)                                                     \
    dst = (unsigned)__builtin_amdgcn_mov_dpp((int)(src), 0x120 + (N), 0xF, 0xF, false);

#if __has_builtin(__builtin_amdgcn_permlane16_swap)
#define PLSWAP(A, B)                                                          \
    { uint2v _t = __builtin_amdgcn_permlane16_swap((A), (B), false, false);   \
      (A) = _t[0]; (B) = _t[1]; }
#else
#define PLSWAP(A, B)                                                          \
    asm("s_nop 1\n\tv_permlane16_swap_b32 %0, %1" : "+v"(A), "+v"(B));
#endif

#if __has_builtin(__builtin_amdgcn_fdot2)
#define FDOT(g, W, a)                                                         \
    __builtin_amdgcn_fdot2(__builtin_bit_cast(half2v, (unsigned)(g)), (W), (a), false)
#else
__device__ inline float fdot2_emul(unsigned g, half2v w, float a) {
    half2v v = __builtin_bit_cast(half2v, g);
    a = fmaf((float)v[0], (float)w[0], a);
    return fmaf((float)v[1], (float)w[1], a);
}
#define FDOT(g, W, a) fdot2_emul((g), (W), (a))
#endif

#define STEP(xv, uu)                                                          \
    {                                                                         \
        unsigned g1,g2,g3,g4,g5,g6,g7,g8,g9,g10,g11,g12,g13,g14,g15;          \
        RORD(g1,c,1)   RORD(g2,c,2)   RORD(g3,c,3)   RORD(g4,c,4)             \
        RORD(g5,c,5)   RORD(g6,c,6)   RORD(g7,c,7)   RORD(g8,c,8)             \
        RORD(g9,c,9)   RORD(g10,c,10) RORD(g11,c,11) RORD(g12,c,12)           \
        RORD(g13,c,13) RORD(g14,c,14) RORD(g15,c,15)                          \
        float a0 = FDOT(c,  W0, (xv));                                        \
        float a1 = FDOT(g1, W1, bch);                                         \
        float a2 = FDOT(g2, W2, 0.0f);                                        \
        float a3 = FDOT(g3, W3, 0.0f);                                        \
        a0 = FDOT(g4,  W4,  a0);  a1 = FDOT(g5,  W5,  a1);                    \
        a2 = FDOT(g6,  W6,  a2);  a3 = FDOT(g7,  W7,  a3);                    \
        a0 = FDOT(g8,  W8,  a0);  a1 = FDOT(g9,  W9,  a1);                    \
        a2 = FDOT(g10, W10, a2);  a3 = FDOT(g11, W11, a3);                    \
        a0 = FDOT(g12, W12, a0);  a1 = FDOT(g13, W13, a1);                    \
        a2 = FDOT(g14, W14, a2);  a3 = FDOT(g15, W15, a3);                    \
        const float A_ = (a0 + a1) + (a2 + a3);                               \
        const float p_ = __builtin_amdgcn_exp2f(A_);                          \
        rr = __builtin_amdgcn_rcpf(p_ + 1.0f);                                \
        pbuf[uu][hh] = fmaf(rr, w2o, wo);                                     \
        unsigned P0 = __builtin_bit_cast(unsigned, rr), P1 = P0;              \
        PLSWAP(P0, P1)                                                        \
        const float rrp = __builtin_bit_cast(float, psel ? P0 : P1);          \
        const float ev = rodd ? rrp : rr;                                     \
        const float od = rodd ? rr : rrp;                                     \
        c = __builtin_bit_cast(unsigned, __builtin_amdgcn_cvt_pkrtz(ev, od)); \
    }

// bf16x8 -> two float4 (widening, exact)
#define CVT8(dlo, dhi, src)                                                   \
    dlo.x = (float)(src)[0]; dlo.y = (float)(src)[1];                         \
    dlo.z = (float)(src)[2]; dlo.w = (float)(src)[3];                         \
    dhi.x = (float)(src)[4]; dhi.y = (float)(src)[5];                         \
    dhi.z = (float)(src)[6]; dhi.w = (float)(src)[7];

// phase-1 tile: global loads -> regs (own batch b)
#define TILE_LOAD(lt)                                                         \
    do {                                                                      \
        const float* xp_ = x + ((size_t)b * Tc + (lt) * 16 + m2) * Ic + r * 8;\
        Xa0 = ((const float4*)xp_)[0];                                        \
        Xa1 = ((const float4*)xp_)[1];                                        \
        Xa2 = ((const float4*)(xp_ + 32))[0];                                 \
        Xa3 = ((const float4*)(xp_ + 32))[1];                                 \
    } while (0)

// phase-1 tile: MFMA + bias + bf16 pack + LDS store into xt buffer `tp`
// (R7-verified D layout: col=lane&15 -> h, row=r*4+reg -> t-in-tile)
#define TILE_MFMA(tp)                                                         \
    do {                                                                      \
        const bf16x8 A0_ = to_bf16x8(Xa0, Xa1);                               \
        const bf16x8 A1_ = to_bf16x8(Xa2, Xa3);                               \
        f32x4 ac0 = {0.f, 0.f, 0.f, 0.f};                                     \
        f32x4 ac1 = {0.f, 0.f, 0.f, 0.f};                                     \
        ac0 = __builtin_amdgcn_mfma_f32_16x16x32_bf16(A0_, Bf[0][0], ac0, 0, 0, 0); \
        ac0 = __builtin_amdgcn_mfma_f32_16x16x32_bf16(A1_, Bf[0][1], ac0, 0, 0, 0); \
        ac1 = __builtin_amdgcn_mfma_f32_16x16x32_bf16(A0_, Bf[1][0], ac1, 0, 0, 0); \
        ac1 = __builtin_amdgcn_mfma_f32_16x16x32_bf16(A1_, Bf[1][1], ac1, 0, 0, 0); \
        bf16x4 p0_, p1_;                                                      \
        p0_[0] = (__bf16)(ac0[0] + bias0); p0_[1] = (__bf16)(ac0[1] + bias0); \
        p0_[2] = (__bf16)(ac0[2] + bias0); p0_[3] = (__bf16)(ac0[3] + bias0); \
        p1_[0] = (__bf16)(ac1[0] + bias1); p1_[1] = (__bf16)(ac1[1] + bias1); \
        p1_[2] = (__bf16)(ac1[2] + bias1); p1_[3] = (__bf16)(ac1[3] + bias1); \
        *(bf16x4*)&(tp)[m2 * XT_ROW + r * 4]        = p0_;                    \
        *(bf16x4*)&(tp)[(m2 + 16) * XT_ROW + r * 4] = p1_;                    \
    } while (0)

__global__ __launch_bounds__(64, 1) void fused_rnn_kernel(
    const float* __restrict__ x, const float* __restrict__ Wih,
    const float* __restrict__ bih, const float* __restrict__ h0,
    const float* __restrict__ Whh, const float* __restrict__ bhh,
    const float* __restrict__ Wout, const float* __restrict__ bout,
    float* __restrict__ out)
{
    __shared__ __bf16 xt[2 * XT_BUF];   // 3072 B
    __shared__ float  pbuf[16][36];     // 2304 B   (t-slot, h with pad)

    const int lane = threadIdx.x;
    const int m2   = lane & 15;          // lane-in-row / MFMA A-row (t)
    const int r    = lane >> 4;          // row 0..3  (MFMA K-chunk)
    const bool rodd = (r & 1);           // odd-h rows
    const int  hh   = 2 * m2 + (r & 1);  // owned output h
    const int  b    = blockIdx.x;        // one batch per block

    // ---- init: Wih fragments, pre-scaled by L2E2 (full dot adds xv once) --
    bf16x8 Bf[2][2];
#pragma unroll
    for (int nh = 0; nh < 2; ++nh)
#pragma unroll
        for (int kh = 0; kh < 2; ++kh) {
            const float* wp = Wih + (m2 + 16 * nh) * Ic + r * 8 + kh * 32;
            Bf[nh][kh] = to_bf16x8s(((const float4*)wp)[0],
                                    ((const float4*)wp)[1], L2E2);
        }
    const float bias0 = bih[m2] * L2E2;
    const float bias1 = bih[m2 + 16] * L2E2;

    // ---- psel discovery for permlane16_swap (R9-proven) -------------------
    bool psel;
    {
        unsigned d0 = (unsigned)lane, d1 = (unsigned)lane;
        PLSWAP(d0, d1)
        psel = (d0 == (unsigned)(lane ^ 16));
    }

    // ---- index simulation: identical 15-RORD network on packed h-indices --
    unsigned s0p = (unsigned)(2 * m2) | ((unsigned)(2 * m2 + 1) << 16);
    unsigned sk1, sk2, sk3, sk4, sk5, sk6, sk7, sk8, sk9, sk10, sk11, sk12,
             sk13, sk14, sk15;
    RORD(sk1, s0p, 1)   RORD(sk2, s0p, 2)   RORD(sk3, s0p, 3)
    RORD(sk4, s0p, 4)   RORD(sk5, s0p, 5)   RORD(sk6, s0p, 6)
    RORD(sk7, s0p, 7)   RORD(sk8, s0p, 8)   RORD(sk9, s0p, 9)
    RORD(sk10, s0p, 10) RORD(sk11, s0p, 11) RORD(sk12, s0p, 12)
    RORD(sk13, s0p, 13) RORD(sk14, s0p, 14) RORD(sk15, s0p, 15)

    // ---- per-lane permuted f16 weight pairs (own h row, scaled -2*L2E2) ---
    const float cw = -2.0f * L2E2;
    const float* wrh = Whh + hh * Hc;
#define MKW(Wk, sk)                                                           \
    half2v Wk;                                                                \
    {                                                                         \
        const unsigned jl_ = (sk) & 0xFFFFu, jh_ = (sk) >> 16;                \
        Wk[0] = (_Float16)(wrh[jl_] * cw);                                    \
        Wk[1] = (_Float16)(wrh[jh_] * cw);                                    \
    }
    MKW(W0, s0p)  MKW(W1, sk1)  MKW(W2, sk2)   MKW(W3, sk3)
    MKW(W4, sk4)  MKW(W5, sk5)  MKW(W6, sk6)   MKW(W7, sk7)
    MKW(W8, sk8)  MKW(W9, sk9)  MKW(W10, sk10) MKW(W11, sk11)
    MKW(W12, sk12) MKW(W13, sk13) MKW(W14, sk14) MKW(W15, sk15)
#undef MKW

    // bias' = (bhh + rowsum(Whh)) * L2E2 (full, single chain adds it once)
    float rs = 0.f;
#pragma unroll
    for (int j = 0; j < Hc; ++j) rs += wrh[j];
    const float bch = (bhh[hh] + rs) * L2E2;
    const float wo  = Wout[hh];
    const float w2o = -2.0f * wo;
    const float bo  = bout[0];

    // initial state r = (1 - h)/2; pack own pair (no cross-lane needed)
    const float h0e = h0[(size_t)b * Hc + 2 * m2];
    const float h0o = h0[(size_t)b * Hc + 2 * m2 + 1];
    const float re0 = fmaf(-0.5f, h0e, 0.5f);
    const float ro0 = fmaf(-0.5f, h0o, 0.5f);
    unsigned c = __builtin_bit_cast(unsigned, __builtin_amdgcn_cvt_pkrtz(re0, ro0));
    float rr = rodd ? ro0 : re0;
    float* orow = out + (size_t)b * Tc;

    // ---- prologue: tiles 0,1 -> buf0,buf1; stage loads for tile 2 ---------
    float4 Xa0, Xa1, Xa2, Xa3;
    TILE_LOAD(0);
    TILE_MFMA(xt);
    TILE_LOAD(1);
    TILE_MFMA(xt + XT_BUF);
    TILE_LOAD(2);
    __syncthreads();   // single wave; drain LDS writes before reads

    const __bf16* xrbase = xt + hh * XT_ROW;

    // xvals for tile 0
    bf16x8 na0 = *(const bf16x8*)(xrbase), na1 = *(const bf16x8*)(xrbase + 8);
    float4 qa0, qa1, qa2, qa3;
    CVT8(qa0, qa1, na0) CVT8(qa2, qa3, na1)

#pragma unroll 1
    for (int tb = 0; tb < Tc / 16; ++tb) {
        // prefetch xvals for tile tb+1 (written during tb-1); clamp at end
        const int tbn = (tb + 1 < Tc / 16) ? tb + 1 : tb;
        const __bf16* xr = xrbase + (tbn & 1) * XT_BUF;
        na0 = *(const bf16x8*)(xr); na1 = *(const bf16x8*)(xr + 8);

        // fused phase-1: tile tb+2 (regs loaded at tb-1), loads for tb+3
        if (tb + 2 < Tc / 16) { TILE_MFMA(xt + (tb & 1) * XT_BUF); }
        if (tb + 3 < Tc / 16) { TILE_LOAD(tb + 3); }

        STEP(qa0.x, 0)  STEP(qa0.y, 1)  STEP(qa0.z, 2)  STEP(qa0.w, 3)
        STEP(qa1.x, 4)  STEP(qa1.y, 5)  STEP(qa1.z, 6)  STEP(qa1.w, 7)
        STEP(qa2.x, 8)  STEP(qa2.y, 9)  STEP(qa2.z, 10) STEP(qa2.w, 11)
        STEP(qa3.x, 12) STEP(qa3.y, 13) STEP(qa3.z, 14) STEP(qa3.w, 15)

        __builtin_amdgcn_wave_barrier();

        // reduce: lane m (<16) sums the 32 h-partials of t-slot m
        if (lane < 16) {
            const float4* pr = (const float4*)&pbuf[lane][0];
            const float4 s0_ = pr[0], s1_ = pr[1], s2_ = pr[2], s3_ = pr[3];
            const float4 s4_ = pr[4], s5_ = pr[5], s6_ = pr[6], s7_ = pr[7];
            const float s =
                ((((s0_.x + s0_.y) + (s0_.z + s0_.w)) +
                  ((s1_.x + s1_.y) + (s1_.z + s1_.w))) +
                 (((s2_.x + s2_.y) + (s2_.z + s2_.w)) +
                  ((s3_.x + s3_.y) + (s3_.z + s3_.w)))) +
                ((((s4_.x + s4_.y) + (s4_.z + s4_.w)) +
                  ((s5_.x + s5_.y) + (s5_.z + s5_.w))) +
                 (((s6_.x + s6_.y) + (s6_.z + s6_.w)) +
                  ((s7_.x + s7_.y) + (s7_.z + s7_.w))));
            orow[tb * 16 + lane] = s + bo;
        }
        __builtin_amdgcn_wave_barrier();

        CVT8(qa0, qa1, na0) CVT8(qa2, qa3, na1)
    }

    // h_last: [1, B, H] appended after outs [B, T, 1]; h = 1 - 2r
    // (two lanes per h write the identical value -- benign)
    if (lane < 32) {
        out[(size_t)Bc * Tc + (size_t)b * Hc + hh] = fmaf(-2.0f, rr, 1.0f);
    }
}

extern "C" void kernel_launch(void* const* d_in, const int* in_sizes, int n_in,
                              void* d_out, int out_size, void* d_ws, size_t ws_size,
                              hipStream_t stream) {
    const float* x    = (const float*)d_in[0];
    const float* h0   = (const float*)d_in[1];
    const float* Wih  = (const float*)d_in[2];
    const float* bih  = (const float*)d_in[3];
    const float* Whh  = (const float*)d_in[4];
    const float* bhh  = (const float*)d_in[5];
    const float* Wout = (const float*)d_in[6];
    const float* bout = (const float*)d_in[7];
    float* out = (float*)d_out;

    fused_rnn_kernel<<<Bc, 64, 0, stream>>>(x, Wih, bih, h0, Whh, bhh,
                                            Wout, bout, out);
}